// Round 6
// baseline (240.009 us; speedup 1.0000x reference)
//
#include <hip/hip_runtime.h>

// Adaptive embedding: partition tokens by cluster (wave-aggregated atomics),
// then gathered bf16-MFMA GEMM per cluster.
//   out[tok,:] = 32 * emb_c[id] @ proj_c^T   (fp32 in, bf16 MFMA, fp32 out)
//
// Round-6: empirical law from R0/R2/R5: time ≈ 5-6.5ns x total K-chunk count,
// nearly independent of per-chunk payload (latency/barrier-convoy bound).
// So: keep R5's proven glds + swizzle + 2-phase __syncthreads pipeline
// (race-free) and MAXIMIZE tile area per chunk: 128x128 tile, K-step 32.
//   chunks: 18736 (R5) -> ~4700.
//  - LDS = 2 bufs x (A[128][32] + B[128][32]) fp32 = 64 KB -> 2 blocks/CU.
//  - smTok/smRow arrays dropped (LDS scratch phase -> regs; epilogue re-reads
//    list[]) to fit 64 KB exactly.
//  - cluster 3 (D=16) folded into the template: clamped sources + zeroed
//    B-fragments for quad>=2 (k>=16).
//
// d_in[0] ids i32[16384]; (emb_i f32[*,d_i], proj_i f32[1024,d_i]), d_i=1024/256/64/16
// out f32 [16384,1024]. ws: int cnt[4]; int lists[4][16384].

constexpr int NTOK  = 16384;
constexpr int DPROJ = 1024;
constexpr float EMB_SCALE = 32.0f;
constexpr int SLOTX = 136;    // >= worst-case slots (128+3), multiple of 8

typedef __attribute__((ext_vector_type(8))) short short8;   // 8 bf16
typedef __attribute__((ext_vector_type(4))) float float4v;  // MFMA C/D

__global__ __launch_bounds__(256) void partition_kernel(
    const int* __restrict__ ids, int* __restrict__ cnt, int* __restrict__ lists)
{
    int t = blockIdx.x * 256 + threadIdx.x;
    int id = ids[t];
    int c = (id >= 200000) ? 3 : (id >= 40000) ? 2 : (id >= 20000) ? 1 : 0;
    int lane = threadIdx.x & 63;
    unsigned long long lt = (1ull << lane) - 1ull;
    int pos = 0;
#pragma unroll
    for (int i = 0; i < 4; ++i) {
        unsigned long long m = __ballot(c == i);
        int b = 0;
        if (lane == 0 && m) b = atomicAdd(&cnt[i], (int)__popcll(m));
        b = __shfl(b, 0);
        if (c == i) pos = b + (int)__popcll(m & lt);
    }
    lists[c * NTOK + pos] = t;
}

__device__ __forceinline__ void gload_lds16(const float* g, void* l) {
    __builtin_amdgcn_global_load_lds(
        (const __attribute__((address_space(1))) void*)g,
        (__attribute__((address_space(3))) void*)l, 16, 0, 0);
}

__device__ __forceinline__ short f2bf(float f) {  // RNE; inputs finite
    unsigned u = __builtin_bit_cast(unsigned, f);
    u += 0x7FFFu + ((u >> 16) & 1u);
    return (short)(u >> 16);
}

__device__ __forceinline__ short8 cvt8f(float4 a, float4 b) {
    short8 r = { f2bf(a.x), f2bf(a.y), f2bf(a.z), f2bf(a.w),
                 f2bf(b.x), f2bf(b.y), f2bf(b.z), f2bf(b.w) };
    return r;
}

// 128(tokens) x 128(cols) tile, 4 waves; wave w owns cols [w*32, w*32+32)
// over all 128 rows (8 m-frags x 2 n-frags = 16 MFMA per chunk per wave).
// LDS: fp32 A[128][32], B[128][32] per buffer, 2 buffers (64 KB total).
// Swizzle (proven R5): physical 16B block p of row r holds logical k-block
// l = p ^ (r&7); glds dest linear, source pre-swizzled, reads swizzled.
template<int D, int NC>
__device__ __forceinline__ void gemm_pipe(
    const int* __restrict__ ids, const float* __restrict__ emb,
    const float* __restrict__ proj, const int* __restrict__ list,
    int count, int lo, int mtile, int n0,
    float* __restrict__ out, char* smem)
{
    const int m0 = mtile * 128;
    if (m0 >= count) return;
    const int tid = threadIdx.x, lane = tid & 63, wv = tid >> 6;
    const int col = lane & 15, quad = lane >> 4;

    // Phase 0: token->emb-row map through LDS scratch (overlaps A buffer,
    // consumed into registers before any staging).
    int* tmp = (int*)smem;
    if (tid < 128) {
        int m = m0 + tid;
        int tok = (m < count) ? list[m] : 0;
        tmp[tid] = (m < count) ? (ids[tok] - lo) : 0;
    }
    __syncthreads();

    int LL[4], rowA[4];
#pragma unroll
    for (int i = 0; i < 4; ++i) {
        LL[i] = i * 4096 + wv * 1024 + lane * 16;   // byte in 16 KB tile
        rowA[i] = tmp[LL[i] >> 7];                  // row = L>>7 (128B rows)
    }
    __syncthreads();   // tmp consumed; buffers free

    float (*As)[4096] = (float(*)[4096])smem;                 // 2 x 16 KB
    float (*Bs)[4096] = (float(*)[4096])(smem + 2 * 16384);   // 2 x 16 KB

    const float* srcA[4]; const float* srcB[4];
#pragma unroll
    for (int i = 0; i < 4; ++i) {
        int L = LL[i];
        int row = L >> 7;
        int kb = ((L >> 4) & 7) ^ (row & 7);        // logical k-block
        int ka = (D >= 32 || kb * 4 < D) ? kb * 4 : 0;  // clamp (D==16): junk
        srcA[i] = emb  + (size_t)rowA[i] * D + ka;      //  blocks are zeroed
        srcB[i] = proj + (size_t)(n0 + row) * D + ka;   //  via B-frag mask
    }

    auto issue = [&](int c, int buf) {   // 8 glds/thread/chunk (4 A + 4 B)
        const int co = c * 32;
#pragma unroll
        for (int i = 0; i < 4; ++i) gload_lds16(srcA[i] + co, (char*)As[buf] + LL[i]);
#pragma unroll
        for (int i = 0; i < 4; ++i) gload_lds16(srcB[i] + co, (char*)Bs[buf] + LL[i]);
    };

    float4v acc[8][2] = {};
    auto compute = [&](int buf) {
        short8 bf[2];
#pragma unroll
        for (int n = 0; n < 2; ++n) {
            int row = wv * 32 + n * 16 + col;
            const float* Bb = Bs[buf] + row * 32;
            float4 x = *(const float4*)(Bb + (((2 * quad + 0) ^ (row & 7)) << 2));
            float4 y = *(const float4*)(Bb + (((2 * quad + 1) ^ (row & 7)) << 2));
            if (D == 16 && quad >= 2) { x = float4{}; y = float4{}; }  // k>=16 pad
            bf[n] = cvt8f(x, y);
        }
#pragma unroll
        for (int m = 0; m < 8; ++m) {
            int row = m * 16 + col;
            const float* Ab = As[buf] + row * 32;
            float4 x = *(const float4*)(Ab + (((2 * quad + 0) ^ (row & 7)) << 2));
            float4 y = *(const float4*)(Ab + (((2 * quad + 1) ^ (row & 7)) << 2));
            short8 af = cvt8f(x, y);
#pragma unroll
            for (int n = 0; n < 2; ++n)
                acc[m][n] = __builtin_amdgcn_mfma_f32_16x16x32_bf16(
                    af, bf[n], acc[m][n], 0, 0, 0);
        }
    };

    // 2-phase pipeline (proven race-free in R5): prefetch next chunk during
    // current compute; __syncthreads() = full drain + barrier.
    issue(0, 0);
    __syncthreads();
#pragma unroll 2
    for (int k = 0; k < NC; ++k) {
        if (k + 1 < NC) issue(k + 1, (k + 1) & 1);
        compute(k & 1);
        __syncthreads();
    }

    // C/D layout: col = lane&15, row = quad*4 + reg.  Token ids re-read from
    // list[] (L1-hot: each element read by 16 lanes).
#pragma unroll
    for (int m = 0; m < 8; ++m) {
#pragma unroll
        for (int r = 0; r < 4; ++r) {
            int mm = m * 16 + quad * 4 + r;
            if (m0 + mm >= count) continue;
            int tok = list[m0 + mm];
            float* op = out + (size_t)tok * DPROJ + n0 + wv * 32 + col;
            op[0]  = acc[m][0][r] * EMB_SCALE;
            op[16] = acc[m][1][r] * EMB_SCALE;
        }
    }
}

__global__ __launch_bounds__(256) void adaptive_emb_gemm(
    const int* __restrict__ ids,
    const float* __restrict__ e0, const float* __restrict__ p0,
    const float* __restrict__ e1, const float* __restrict__ p1,
    const float* __restrict__ e2, const float* __restrict__ p2,
    const float* __restrict__ e3, const float* __restrict__ p3,
    const int* __restrict__ cnt, const int* __restrict__ lists,
    float* __restrict__ out)
{
    __shared__ __align__(16) char smem[65536];   // 2 bufs x (16K A + 16K B)

    const int n0 = blockIdx.y * 128;
    int c0t = (cnt[0] + 127) >> 7;
    int c1t = (cnt[1] + 127) >> 7;
    int c2t = (cnt[2] + 127) >> 7;
    int c3t = (cnt[3] + 127) >> 7;
    int s = blockIdx.x;
    if (s < c0t) {
        gemm_pipe<1024, 32>(ids, e0, p0, lists, cnt[0], 0, s, n0, out, smem);
        return;
    }
    s -= c0t;
    if (s < c1t) {
        gemm_pipe<256, 8>(ids, e1, p1, lists + NTOK, cnt[1], 20000, s, n0, out, smem);
        return;
    }
    s -= c1t;
    if (s < c2t) {
        gemm_pipe<64, 2>(ids, e2, p2, lists + 2 * NTOK, cnt[2], 40000, s, n0, out, smem);
        return;
    }
    s -= c2t;
    if (s < c3t)
        gemm_pipe<16, 1>(ids, e3, p3, lists + 3 * NTOK, cnt[3], 200000, s, n0, out, smem);
}

extern "C" void kernel_launch(void* const* d_in, const int* in_sizes, int n_in,
                              void* d_out, int out_size, void* d_ws, size_t ws_size,
                              hipStream_t stream) {
    const int*   ids = (const int*)d_in[0];
    const float* e0  = (const float*)d_in[1];
    const float* p0  = (const float*)d_in[2];
    const float* e1  = (const float*)d_in[3];
    const float* p1  = (const float*)d_in[4];
    const float* e2  = (const float*)d_in[5];
    const float* p2  = (const float*)d_in[6];
    const float* e3  = (const float*)d_in[7];
    const float* p3  = (const float*)d_in[8];
    float* out = (float*)d_out;

    int* cnt   = (int*)d_ws;
    int* lists = cnt + 4;

    (void)hipMemsetAsync(cnt, 0, 4 * sizeof(int), stream);
    partition_kernel<<<dim3(NTOK / 256), 256, 0, stream>>>(ids, cnt, lists);

    // x = flat slot (cluster/m-tile decoded from cnt[] on device, c0 first),
    // y = n-tile (8 x 128 cols).  y-stride in linear block id = 136 (mult of
    // 8) -> one m-tile's n-blocks land on one XCD -> emb gather is L2-local.
    adaptive_emb_gemm<<<dim3(SLOTX, DPROJ / 128), 256, 0, stream>>>(
        ids, e0, p0, e1, p1, e2, p2, e3, p3, cnt, lists, out);
}

// Round 7
// 220.535 us; speedup vs baseline: 1.0883x; 1.0883x over previous
//
#include <hip/hip_runtime.h>

// Adaptive embedding: partition tokens by cluster (wave-aggregated atomics,
// + zero cluster-0 output rows), then gathered bf16-MFMA GEMM per cluster:
//   out[tok,:] = 32 * emb_c[id] @ proj_c^T   (fp32 in, bf16 MFMA, fp32 out)
//
// Round-7 = Round-0 (proven best, 61us GEMM) + ONE change: split-K x4 for
// cluster 0 (serial K-chain 32 -> 8 chunks, 160 -> 640 c0 blocks).  c0
// blocks atomicAdd into rows pre-zeroed by the partition kernel; clusters
// 1-3 keep plain stores.  All tile/staging/barrier structure is R0-identical.
//
// d_in[0] ids i32[16384]; (emb_i f32[*,d_i], proj_i f32[1024,d_i]), d_i=1024/256/64/16
// out f32 [16384,1024]. ws: int cnt[4]; int lists[4][16384].

constexpr int NTOK  = 16384;
constexpr int DPROJ = 1024;
constexpr float EMB_SCALE = 32.0f;

typedef __attribute__((ext_vector_type(8))) short short8;   // 8 bf16 (4 VGPR)
typedef __attribute__((ext_vector_type(4))) float float4v;  // MFMA C/D

__global__ __launch_bounds__(256) void partition_kernel(
    const int* __restrict__ ids, int* __restrict__ cnt, int* __restrict__ lists,
    float* __restrict__ out)
{
    int t = blockIdx.x * 256 + threadIdx.x;
    int id = ids[t];
    int c = (id >= 200000) ? 3 : (id >= 40000) ? 2 : (id >= 20000) ? 1 : 0;
    int lane = threadIdx.x & 63;
    unsigned long long lt = (1ull << lane) - 1ull;
    int pos = 0;
#pragma unroll
    for (int i = 0; i < 4; ++i) {
        unsigned long long m = __ballot(c == i);
        int b = 0;
        if (lane == 0 && m) b = atomicAdd(&cnt[i], (int)__popcll(m));
        b = __shfl(b, 0);
        if (c == i) pos = b + (int)__popcll(m & lt);
    }
    lists[c * NTOK + pos] = t;

    // Zero out-rows of cluster-0 tokens: split-K GEMM blocks atomicAdd them.
    // Wave-cooperative: 64 lanes x 4 float4 = 4 KB per token row.
    unsigned long long mz = __ballot(c == 0);
    int wbase = t & ~63;
    while (mz) {
        int src = __ffsll(mz) - 1; mz &= mz - 1;
        float4* op = (float4*)(out + (size_t)(wbase + src) * DPROJ);
        float4 z = {0.f, 0.f, 0.f, 0.f};
#pragma unroll
        for (int j = 0; j < 4; ++j) op[lane + 64 * j] = z;
    }
}

__device__ __forceinline__ short f2bf(float f) {  // RNE; inputs finite
    unsigned u = __builtin_bit_cast(unsigned, f);
    u += 0x7FFFu + ((u >> 16) & 1u);
    return (short)(u >> 16);
}

// 64(tokens) x 128(cols) tile, 4 waves; wave w owns cols [w*32, w*32+32).
// BK=32 chunk staged fp32->bf16 into LDS [rows][40] (pad 8 -> <=2-way banks).
// NC chunks starting at K-offset kbase*32 (split-K for cluster 0).
template<int D, int NC, bool ATOMIC>
__device__ __forceinline__ void gemm_tile(
    const int* __restrict__ ids,
    const float* __restrict__ emb,
    const float* __restrict__ proj,
    const int* __restrict__ list,
    int count, int lo, int kbase,
    float* __restrict__ out,
    short (*Asm)[40], short (*Bsm)[40], int* smTok, int* smRow)
{
    const int m0 = blockIdx.y * 64;
    if (m0 >= count) return;
    const int n0 = blockIdx.x * 128;
    const int tid  = threadIdx.x;
    const int lane = tid & 63;
    const int wv   = tid >> 6;
    const int col  = lane & 15;
    const int quad = lane >> 4;

    if (tid < 64) {
        int m = m0 + tid;
        int tok = (m < count) ? list[m] : -1;
        smTok[tid] = tok;
        smRow[tid] = (tok >= 0) ? (ids[tok] - lo) : 0;
    }
    __syncthreads();

    const int ar = tid >> 2, ac = (tid & 3) * 8;    // A: 8 floats/thread
    const int br = tid >> 1, bc = (tid & 1) * 16;   // B: 16 floats/thread
    const float* arow = emb  + (size_t)smRow[ar] * D + ac;
    const float* brow = proj + (size_t)(n0 + br) * D + bc;

    float4v acc[4][2] = {};

    for (int kc = 0; kc < NC; ++kc) {
        const int k0 = (kbase + kc) * 32;
        float4 a0 = {}, a1 = {}, b0 = {}, b1 = {}, b2 = {}, b3 = {};
        if (D >= 32 || ac + 0  < D) a0 = *(const float4*)(arow + k0);
        if (D >= 32 || ac + 4  < D) a1 = *(const float4*)(arow + k0 + 4);
        if (D >= 32 || bc + 0  < D) b0 = *(const float4*)(brow + k0);
        if (D >= 32 || bc + 4  < D) b1 = *(const float4*)(brow + k0 + 4);
        if (D >= 32 || bc + 8  < D) b2 = *(const float4*)(brow + k0 + 8);
        if (D >= 32 || bc + 12 < D) b3 = *(const float4*)(brow + k0 + 12);
        if (D == 16) {  // zero-pad cols >= 16
            if (ac >= 16) { a0 = float4{}; a1 = float4{}; }
            if (bc >= 16) { b0 = float4{}; b1 = float4{}; b2 = float4{}; b3 = float4{}; }
        }
        __syncthreads();   // previous chunk's frag reads done
        {
            short8 va = { f2bf(a0.x), f2bf(a0.y), f2bf(a0.z), f2bf(a0.w),
                          f2bf(a1.x), f2bf(a1.y), f2bf(a1.z), f2bf(a1.w) };
            *(short8*)&Asm[ar][ac] = va;
            short8 vb0 = { f2bf(b0.x), f2bf(b0.y), f2bf(b0.z), f2bf(b0.w),
                           f2bf(b1.x), f2bf(b1.y), f2bf(b1.z), f2bf(b1.w) };
            short8 vb1 = { f2bf(b2.x), f2bf(b2.y), f2bf(b2.z), f2bf(b2.w),
                           f2bf(b3.x), f2bf(b3.y), f2bf(b3.z), f2bf(b3.w) };
            *(short8*)&Bsm[br][bc]     = vb0;
            *(short8*)&Bsm[br][bc + 8] = vb1;
        }
        __syncthreads();

        short8 af[4], bf[2];
#pragma unroll
        for (int m = 0; m < 4; ++m)
            af[m] = *(const short8*)&Asm[m * 16 + col][quad * 8];
#pragma unroll
        for (int n = 0; n < 2; ++n)
            bf[n] = *(const short8*)&Bsm[wv * 32 + n * 16 + col][quad * 8];
#pragma unroll
        for (int m = 0; m < 4; ++m)
#pragma unroll
            for (int n = 0; n < 2; ++n)
                acc[m][n] = __builtin_amdgcn_mfma_f32_16x16x32_bf16(
                    af[m], bf[n], acc[m][n], 0, 0, 0);
    }

    // C/D layout: col = lane&15, row = quad*4 + reg
#pragma unroll
    for (int m = 0; m < 4; ++m) {
#pragma unroll
        for (int r = 0; r < 4; ++r) {
            int tok = smTok[m * 16 + quad * 4 + r];
            if (tok < 0) continue;
            float* op = out + (size_t)tok * DPROJ + n0 + wv * 32 + col;
            if constexpr (ATOMIC) {
                atomicAdd(op,      acc[m][0][r] * EMB_SCALE);
                atomicAdd(op + 16, acc[m][1][r] * EMB_SCALE);
            } else {
                op[0]  = acc[m][0][r] * EMB_SCALE;
                op[16] = acc[m][1][r] * EMB_SCALE;
            }
        }
    }
}

__global__ __launch_bounds__(256) void adaptive_emb_gemm(
    const int* __restrict__ ids,
    const float* __restrict__ e0, const float* __restrict__ p0,
    const float* __restrict__ e1, const float* __restrict__ p1,
    const float* __restrict__ e2, const float* __restrict__ p2,
    const float* __restrict__ e3, const float* __restrict__ p3,
    const int* __restrict__ cnt, const int* __restrict__ lists,
    float* __restrict__ out)
{
    __shared__ short Asm[64][40];
    __shared__ short Bsm[128][40];
    __shared__ int smTok[64];
    __shared__ int smRow[64];

    const int z = blockIdx.z;
    if (z < 4) {        // cluster 0: split-K x4, K-chunks [z*8, z*8+8)
        gemm_tile<1024, 8, true>(ids, e0, p0, lists, cnt[0], 0, z * 8,
                                 out, Asm, Bsm, smTok, smRow);
    } else if (z == 4) {
        gemm_tile<256, 8, false>(ids, e1, p1, lists + NTOK, cnt[1], 20000, 0,
                                 out, Asm, Bsm, smTok, smRow);
    } else if (z == 5) {
        gemm_tile<64, 2, false>(ids, e2, p2, lists + 2 * NTOK, cnt[2], 40000, 0,
                                out, Asm, Bsm, smTok, smRow);
    } else {
        gemm_tile<16, 1, false>(ids, e3, p3, lists + 3 * NTOK, cnt[3], 200000, 0,
                                out, Asm, Bsm, smTok, smRow);
    }
}

extern "C" void kernel_launch(void* const* d_in, const int* in_sizes, int n_in,
                              void* d_out, int out_size, void* d_ws, size_t ws_size,
                              hipStream_t stream) {
    const int*   ids = (const int*)d_in[0];
    const float* e0  = (const float*)d_in[1];
    const float* p0  = (const float*)d_in[2];
    const float* e1  = (const float*)d_in[3];
    const float* p1  = (const float*)d_in[4];
    const float* e2  = (const float*)d_in[5];
    const float* p2  = (const float*)d_in[6];
    const float* e3  = (const float*)d_in[7];
    const float* p3  = (const float*)d_in[8];
    float* out = (float*)d_out;

    int* cnt   = (int*)d_ws;
    int* lists = cnt + 4;

    (void)hipMemsetAsync(cnt, 0, 4 * sizeof(int), stream);
    partition_kernel<<<dim3(NTOK / 256), 256, 0, stream>>>(ids, cnt, lists, out);

    // x = n-tile (8), y = m-tile (worst case 256), z = 0..3 c0 ksegs, 4..6 c1-c3.
    adaptive_emb_gemm<<<dim3(DPROJ / 128, NTOK / 64, 7), 256, 0, stream>>>(
        ids, e0, p0, e1, p1, e2, p2, e3, p3, cnt, lists, out);
}